// Round 15
// baseline (148.324 us; speedup 1.0000x reference)
//
#include <hip/hip_runtime.h>
#include <hip/hip_bf16.h>
#include <math.h>

// Problem constants
#define T_SEQ 4096
#define DIM   1024
#define NH    8
#define HDIM  64
#define ETA   4
#define NR    7
#define NKQVC 2688   // combined: 2560 kqv + 96 p + 32 pad
#define CHUNK 16
#define NCHUNK 256   // T_SEQ / CHUNK

typedef __attribute__((ext_vector_type(8))) short bf16x8;
typedef __attribute__((ext_vector_type(4))) short short4v;
typedef __attribute__((ext_vector_type(4))) float f32x4;

// Workspace layout (float offsets).
// Permanent:
#define KQVC_OFF    0ul          // combined kqv+p bf16: 4096*2688 sh = 5,505,024 fl
#define OCC_OFF     5505024ul    // occ f32: 4096*8 = 32,768 fl
#define BTPROJ_OFF  5537792ul    // W_proj^T bf16: 1024*512 sh = 262,144 fl
#define ATTNBF_OFF  5799936ul    // attn bf16: 4096*512 sh = 1,048,576 fl
#define BIASC_OFF   6848512ul    // concat bias f32: 2,816 fl
// Transient A (dead after input GEMM):
#define ABF_OFF     6851328ul    // inputs bf16: 2,097,152 fl
#define BTCAT_OFF   8948480ul    // [2688][1024] bf16 = 1,376,256 fl
// Transient B (overlays transient A after GEMM), bf16:
#define YSUM_OFF    6851328ul    // 256*8*44*64 sh = 2,883,584 fl
#define CARRY_OFF   9734912ul    // 256*8*39*64 sh = 2,555,904 fl

// Output layout (float offsets), concatenated in return order
#define O_ATTN 0ul
#define O_FK   4194304ul   // (7,8,256)
#define O_FV   4208640ul   // (7,8,64)
#define O_FS   4212224ul   // (8,256)
#define O_TICK 4214272ul   // (1,)

__device__ __forceinline__ float sigm(float x) { return 1.f / (1.f + __expf(-x)); }

__device__ __forceinline__ short f2bf(float f) {
  union { __hip_bfloat16 b; short s; } u;
  u.b = __float2bfloat16(f);
  return u.s;
}
__device__ __forceinline__ float bf2f(short s) {
  union { __hip_bfloat16 b; short s2; } u;
  u.s2 = s;
  return __bfloat162float(u.b);
}

__device__ __forceinline__ void gload16(const void* g, void* l) {
  __builtin_amdgcn_global_load_lds(
      (const __attribute__((address_space(1))) void*)g,
      (__attribute__((address_space(3))) void*)l, 16, 0, 0);
}

// ---------------------------------------------------------------------------
// Fused prologue: one dispatch replaces cast + 3 transposes + bias + occil.
// ---------------------------------------------------------------------------
__global__ __launch_bounds__(256) void prologue(
    const float* __restrict__ inputs, short* __restrict__ Abf,
    const float* __restrict__ W_kqv, const float* __restrict__ W_p,
    const float* __restrict__ W_proj, short* __restrict__ BtCat,
    short* __restrict__ BtProj, const float* __restrict__ b_kqv,
    const float* __restrict__ b_p, float* __restrict__ biasc,
    const float* __restrict__ tick, float* __restrict__ occ) {
  const int b = blockIdx.x;
  const int tid = threadIdx.x;
  __shared__ float tile[32][33];
  const int tx = tid & 31, ty = tid >> 5;

  if (b < 4096) {
    size_t i = ((size_t)b * 256 + tid) * 4;
    float4 v = *(const float4*)(inputs + i);
    short4v o;
    o.x = f2bf(v.x); o.y = f2bf(v.y); o.z = f2bf(v.z); o.w = f2bf(v.w);
    *(short4v*)(Abf + i) = o;
  } else if (b < 6656) {
    int blk = b - 4096;
    int n0 = (blk % 80) * 32, k0 = (blk / 80) * 32;
    for (int i = ty; i < 32; i += 8)
      tile[i][tx] = W_kqv[(size_t)(k0 + i) * 2560 + n0 + tx];
    __syncthreads();
    for (int i = ty; i < 32; i += 8)
      BtCat[(size_t)(n0 + i) * 1024 + k0 + tx] = f2bf(tile[tx][i]);
  } else if (b < 6752) {
    int blk = b - 6656;
    int n0 = (blk % 3) * 32, k0 = (blk / 3) * 32;
    for (int i = ty; i < 32; i += 8)
      tile[i][tx] = W_p[(size_t)(k0 + i) * 96 + n0 + tx];
    __syncthreads();
    short* dst = BtCat + (size_t)2560 * 1024;
    for (int i = ty; i < 32; i += 8)
      dst[(size_t)(n0 + i) * 1024 + k0 + tx] = f2bf(tile[tx][i]);
  } else if (b < 7264) {
    int blk = b - 6752;
    int n0 = (blk % 32) * 32, k0 = (blk / 32) * 32;
    for (int i = ty; i < 32; i += 8)
      tile[i][tx] = W_proj[(size_t)(k0 + i) * 1024 + n0 + tx];
    __syncthreads();
    for (int i = ty; i < 32; i += 8)
      BtProj[(size_t)(n0 + i) * 512 + k0 + tx] = f2bf(tile[tx][i]);
  } else if (b < 7275) {
    int i = (b - 7264) * 256 + tid;
    if (i < NKQVC)
      biasc[i] = (i < 2560) ? b_kqv[i] : (i < 2656 ? b_p[i - 2560] : 0.f);
  } else {
    int t = (b - 7275) * 256 + tid;
    float tickt = tick[0] + (float)(t + 1);
#pragma unroll
    for (int r = 0; r < NR; ++r) {
      float om = (float)(-3.14159265358979323846 + r * (3.14159265358979323846 / 3.0));
      occ[t * 8 + r] = cosf(tickt * om);
    }
    occ[t * 8 + 7] = 0.f;
  }
}

// ---------------------------------------------------------------------------
// MFMA GEMM: C[M,N] = A[M,K] @ Bt[N,K]^T + bias.  A,Bt bf16.
// 64x64 tile, BK=32, 256 threads (4 waves 2x2, each 32x32), 16x16x32 MFMA.
// Grid = (M/64)*(N/64) -> 10.5 blocks/CU for the kqv shape (vs 2.6 at 128²):
// the 128² version was grid-starved (1170 cyc/K-iter stall, R13/R14 PMC).
// Double-buffered LDS (16 KB), one barrier per K-step.
// ---------------------------------------------------------------------------
template <int OUT_BF16>
__global__ __launch_bounds__(256) void gemm_bt_mfma(
    const short* __restrict__ A, const short* __restrict__ Bt,
    const float* __restrict__ bias, void* __restrict__ Cout,
    int M, int N, int K) {
  __shared__ __align__(16) short lds[8192];   // 2 bufs x (As 2048 | Bs 2048)

  // XCD-aware bijective swizzle (grid % 8 == 0)
  int nwg = gridDim.x;
  int cpx = nwg >> 3;
  int bid = blockIdx.x;
  int swz = (bid & 7) * cpx + (bid >> 3);
  int nbx = N >> 6;
  int bm0 = (swz / nbx) << 6;
  int bn0 = (swz % nbx) << 6;

  const int tid = threadIdx.x;
  const int w = tid >> 6, l = tid & 63;
  const int wm = w >> 1, wn = w & 1;
  const int fr = l & 15;
  const int fq = l >> 4;

  // staging: wave w stages rows [16w,16w+16) of A and of B (1 KB each)
  const short* Ag = A + (size_t)(bm0 + w * 16 + (l >> 2)) * K + (l & 3) * 8;
  const short* Bg = Bt + (size_t)(bn0 + w * 16 + (l >> 2)) * K + (l & 3) * 8;

  f32x4 acc[2][2];
#pragma unroll
  for (int mi = 0; mi < 2; ++mi)
#pragma unroll
    for (int ni = 0; ni < 2; ++ni)
#pragma unroll
      for (int r = 0; r < 4; ++r) acc[mi][ni][r] = 0.f;

  const int KT = K >> 5;
  int cur = 0;
  gload16(Ag, &lds[w * 512]);
  gload16(Bg, &lds[2048 + w * 512]);
  __syncthreads();

  for (int kt = 0; kt < KT; ++kt) {
    if (kt + 1 < KT) {
      int nb = (cur ^ 1) * 4096;
      int ko = (kt + 1) * 32;
      gload16(Ag + ko, &lds[nb + w * 512]);
      gload16(Bg + ko, &lds[nb + 2048 + w * 512]);
    }
    const short* ArP = &lds[cur * 4096 + (wm * 32 + fr) * 32 + fq * 8];
    const short* BrP = &lds[cur * 4096 + 2048 + (wn * 32 + fr) * 32 + fq * 8];
    bf16x8 af[2], bfv[2];
#pragma unroll
    for (int mi = 0; mi < 2; ++mi) af[mi] = *(const bf16x8*)(ArP + mi * 512);
#pragma unroll
    for (int ni = 0; ni < 2; ++ni) bfv[ni] = *(const bf16x8*)(BrP + ni * 512);
#pragma unroll
    for (int mi = 0; mi < 2; ++mi)
#pragma unroll
      for (int ni = 0; ni < 2; ++ni)
        acc[mi][ni] = __builtin_amdgcn_mfma_f32_16x16x32_bf16(
            af[mi], bfv[ni], acc[mi][ni], 0, 0, 0);
    __syncthreads();
    cur ^= 1;
  }

  // C/D layout: col = lane&15, row = (lane>>4)*4 + reg  [m89 verified]
  if (OUT_BF16) {
    // stage C tile (64x64 bf16 = 8 KB) in LDS, then coalesced 16B stores
#pragma unroll
    for (int ni = 0; ni < 2; ++ni) {
      int col = wn * 32 + ni * 16 + fr;
      float bz = bias[bn0 + col];
#pragma unroll
      for (int mi = 0; mi < 2; ++mi) {
        int row = wm * 32 + mi * 16 + fq * 4;
#pragma unroll
        for (int r = 0; r < 4; ++r)
          lds[(row + r) * 64 + col] = f2bf(acc[mi][ni][r] + bz);
      }
    }
    __syncthreads();
    int row = tid >> 2, seg = tid & 3;
    const bf16x8* src = (const bf16x8*)&lds[row * 64 + seg * 16];
    short* dst = (short*)Cout + (size_t)(bm0 + row) * N + bn0 + seg * 16;
    *(bf16x8*)dst = src[0];
    *(bf16x8*)(dst + 8) = src[1];
  } else {
#pragma unroll
    for (int ni = 0; ni < 2; ++ni) {
      int col = bn0 + wn * 32 + ni * 16 + fr;
      float bz = bias[col];
#pragma unroll
      for (int mi = 0; mi < 2; ++mi) {
        int row = bm0 + wm * 32 + mi * 16 + fq * 4;
#pragma unroll
        for (int r = 0; r < 4; ++r)
          ((float*)Cout)[(size_t)(row + r) * N + col] = acc[mi][ni][r] + bz;
      }
    }
  }
}

// ---------------------------------------------------------------------------
// Half-chunk gate staging: wave w computes gates for its 2 t's of this half
// at full 64-lane parallelism. Two CONTIGUOUS arrays (16 B/lane stride ->
// conflict-free b128):
//   glA[tt][dd][8] = xs0-3, dg0-3 ; glB[tt][dd][8] = qf0-3, vb, db, pad2.
// ---------------------------------------------------------------------------
__device__ __forceinline__ void stage_gates_half(
    const short* __restrict__ kqv, const int* __restrict__ term,
    short* glA, short* glB, int c, int h, int w, int dd, int half) {
#pragma unroll
  for (int j = 0; j < 2; ++j) {
    int tt = w * 2 + j;                 // 0..7
    int tg = c * CHUNK + half * 8 + tt;
    size_t base = (size_t)tg * NKQVC + h * 320 + dd;
    float kx = bf2f(kqv[base]);
    float qx = bf2f(kqv[base + 64]);
    float vx = bf2f(kqv[base + 128]);
    float bx = bf2f(kqv[base + 192]);
    float gx = bf2f(kqv[base + 256]);
    const short* pp = kqv + (size_t)tg * NKQVC + 2560 + h * 12;
    float nt = 1.f - (float)term[tg];
    float rk = fmaxf(kx, 0.f), rq = fmaxf(qx, 0.f);
    float sg = sigm(gx), sb = sigm(bx);
    bf16x8 oA, oB;
#pragma unroll
    for (int n = 0; n < 4; ++n) {
      float rp1 = fmaxf(bf2f(pp[n]), 0.f);
      float rp2 = fmaxf(bf2f(pp[4 + n]), 0.f);
      float sp3 = sigm(bf2f(pp[8 + n]));
      float gam = sg * sp3;
      oA[n]     = f2bf(rk * rp1 * gam);     // xs
      oA[4 + n] = f2bf((1.f - gam) * nt);   // dg
      oB[n]     = f2bf(rq * rp2);           // qf
    }
    oB[4] = f2bf(vx * sb);                  // vb
    oB[5] = f2bf((1.f - sb) * nt);          // db
    oB[6] = 0; oB[7] = 0;
    *(bf16x8*)&glA[(tt * 64 + dd) * 8] = oA;
    *(bf16x8*)&glB[(tt * 64 + dd) * 8] = oB;
  }
}

// ---------------------------------------------------------------------------
// Pass A (4-wave r-split, half-staged gates): wave w<3 owns r={2w,2w+1};
// wave 3 owns r=6 + fs/Pg/Pb. Per half: stage -> barrier -> scan -> barrier.
// ysum is bf16: [c][h][slot(44)][dd].
// ---------------------------------------------------------------------------
__global__ __launch_bounds__(256) void pass_a(
    const short* __restrict__ kqv, const float* __restrict__ occ,
    const int* __restrict__ term, short* __restrict__ ysum) {
  const int c = blockIdx.x, h = blockIdx.y;
  const int tid = threadIdx.x;
  const int w = tid >> 6, dd = tid & 63;
  const int R0 = w * 2;
  const int RN = (w == 3) ? 1 : 2;
  const bool w3 = (w == 3);
  __shared__ __align__(16) short glA[8 * 64 * 8];  // 8 KB
  __shared__ __align__(16) short glB[8 * 64 * 8];  // 8 KB
  __shared__ float socc[CHUNK][8];
  for (int i = tid; i < CHUNK * 8; i += 256)
    socc[i >> 3][i & 7] = occ[(size_t)c * CHUNK * 8 + i];

  float yk[2][ETA], yv[2], ys[ETA], Pg[ETA], Pb = 1.f;
#pragma unroll
  for (int rr = 0; rr < 2; ++rr) {
    yv[rr] = 0.f;
#pragma unroll
    for (int n = 0; n < ETA; ++n) yk[rr][n] = 0.f;
  }
#pragma unroll
  for (int n = 0; n < ETA; ++n) { ys[n] = 0.f; Pg[n] = 1.f; }

  for (int half = 0; half < 2; ++half) {
    stage_gates_half(kqv, term, glA, glB, c, h, w, dd, half);
    __syncthreads();
    for (int tt = 0; tt < 8; ++tt) {
      int t = half * 8 + tt;
      bf16x8 gA = *(const bf16x8*)&glA[(tt * 64 + dd) * 8];
      bf16x8 gB = *(const bf16x8*)&glB[(tt * 64 + dd) * 8];
      float occr[2];
#pragma unroll
      for (int rr = 0; rr < 2; ++rr)
        occr[rr] = socc[t][(R0 + rr) < 7 ? (R0 + rr) : 7];
#pragma unroll
      for (int n = 0; n < ETA; ++n) {
        float xs = bf2f(gA[n]);
        float dg = bf2f(gA[4 + n]);
        if (w3) {
          Pg[n] *= dg;
          ys[n] = fmaf(ys[n], dg, xs);
        }
#pragma unroll
        for (int rr = 0; rr < 2; ++rr)
          if (rr < RN) yk[rr][n] = fmaf(yk[rr][n], dg, xs * occr[rr]);
      }
      float vb = bf2f(gB[4]);
      float db = bf2f(gB[5]);
      if (w3) Pb *= db;
#pragma unroll
      for (int rr = 0; rr < 2; ++rr)
        if (rr < RN) yv[rr] = fmaf(yv[rr], db, vb * occr[rr]);
    }
    __syncthreads();   // scan done before next half's staging overwrites
  }

  short* o = ysum + (size_t)(c * NH + h) * 44 * 64 + dd;
#pragma unroll
  for (int rr = 0; rr < 2; ++rr)
    if (rr < RN) {
#pragma unroll
      for (int n = 0; n < ETA; ++n) o[((R0 + rr) * 4 + n) * 64] = f2bf(yk[rr][n]);
      o[(28 + R0 + rr) * 64] = f2bf(yv[rr]);
    }
  if (w3) {
#pragma unroll
    for (int n = 0; n < ETA; ++n) o[(35 + n) * 64] = f2bf(ys[n]);
#pragma unroll
    for (int n = 0; n < ETA; ++n) o[(39 + n) * 64] = f2bf(Pg[n]);
    o[43 * 64] = f2bf(Pb);
  }
}

// ---------------------------------------------------------------------------
// Pass B: carry propagation (f32 chain) from bf16 ysum into bf16 carry
// (separate __restrict__ buffer -> ring prefetch PD=16 batches).
// ---------------------------------------------------------------------------
__global__ __launch_bounds__(256) void pass_b(
    const short* __restrict__ ysum, short* __restrict__ carry,
    const float* __restrict__ k_prev, const float* __restrict__ v_prev,
    const float* __restrict__ s_prev) {
  int idx = blockIdx.x * 256 + threadIdx.x;
  int dd = idx & 63;
  int slot = (idx >> 6) % 39;
  int h = idx / (39 * 64);

  int pslot;
  float f;
  if (slot < 28) {
    int r = slot >> 2, n = slot & 3;
    f = k_prev[(size_t)(r * NH + h) * 256 + n * 64 + dd];
    pslot = 39 + n;
  } else if (slot < 35) {
    int r = slot - 28;
    f = v_prev[(size_t)(r * NH + h) * 64 + dd];
    pslot = 43;
  } else {
    int n = slot - 35;
    f = s_prev[(size_t)h * 256 + n * 64 + dd];
    pslot = 39 + n;
  }
  const size_t YSTR = (size_t)NH * 2816;
  const size_t CSTR = (size_t)NH * 2496;
  const short* yb = ysum + (size_t)h * 2816 + slot * 64 + dd;
  const short* pb = ysum + (size_t)h * 2816 + pslot * 64 + dd;
  short* cb = carry + (size_t)h * 2496 + slot * 64 + dd;

#define PD 16
  float yring[PD], pring[PD];
#pragma unroll
  for (int d = 0; d < PD; ++d) {
    yring[d] = bf2f(yb[(size_t)d * YSTR]);
    pring[d] = bf2f(pb[(size_t)d * YSTR]);
  }
  const int NB = NCHUNK / PD;
  for (int cb2 = 0; cb2 < NB; ++cb2) {
    int c0 = cb2 * PD;
    float ynext[PD], pnext[PD];
    if (cb2 + 1 < NB) {
#pragma unroll
      for (int j = 0; j < PD; ++j) {
        ynext[j] = bf2f(yb[(size_t)(c0 + PD + j) * YSTR]);
        pnext[j] = bf2f(pb[(size_t)(c0 + PD + j) * YSTR]);
      }
    }
#pragma unroll
    for (int j = 0; j < PD; ++j) {
      cb[(size_t)(c0 + j) * CSTR] = f2bf(f);
      f = fmaf(f, pring[j], yring[j]);
    }
    if (cb2 + 1 < NB) {
#pragma unroll
      for (int j = 0; j < PD; ++j) { yring[j] = ynext[j]; pring[j] = pnext[j]; }
    }
  }
#undef PD
}

// ---------------------------------------------------------------------------
// Pass C (4-wave r-split, half-staged gates, deferred combine).
// ---------------------------------------------------------------------------
__global__ __launch_bounds__(256) void pass_c(
    const short* __restrict__ kqv, const float* __restrict__ occ,
    const int* __restrict__ term, const short* __restrict__ carry,
    short* __restrict__ attn, float* __restrict__ out,
    const float* __restrict__ tick) {
  const int c = blockIdx.x, h = blockIdx.y;
  const int tid = threadIdx.x;
  const int w = tid >> 6, dd = tid & 63;
  const int R0 = w * 2;
  const int RN = (w == 3) ? 1 : 2;
  const bool w3 = (w == 3);
  __shared__ __align__(16) short glA[8 * 64 * 8];  // 8 KB
  __shared__ __align__(16) short glB[8 * 64 * 8];  // 8 KB
  __shared__ float socc[CHUNK][8];
  __shared__ float xch[5][8][64];   // [w partials 0..3 | denom][tt][dd]
  for (int i = tid; i < CHUNK * 8; i += 256)
    socc[i >> 3][i & 7] = occ[(size_t)c * CHUNK * 8 + i];

  const short* cp = carry + (size_t)(c * NH + h) * 2496 + dd;
  float fk[2][ETA], fv[2], fs[ETA];
#pragma unroll
  for (int rr = 0; rr < 2; ++rr)
    if (rr < RN) {
#pragma unroll
      for (int n = 0; n < ETA; ++n) fk[rr][n] = bf2f(cp[((R0 + rr) * 4 + n) * 64]);
      fv[rr] = bf2f(cp[(28 + R0 + rr) * 64]);
    }
  if (w3) {
#pragma unroll
    for (int n = 0; n < ETA; ++n) fs[n] = bf2f(cp[(35 + n) * 64]);
  }

  for (int half = 0; half < 2; ++half) {
    stage_gates_half(kqv, term, glA, glB, c, h, w, dd, half);
    __syncthreads();   // stage done AND previous combine's xch reads done
    for (int tt = 0; tt < 8; ++tt) {
      int t = half * 8 + tt;
      bf16x8 gA = *(const bf16x8*)&glA[(tt * 64 + dd) * 8];
      bf16x8 gB = *(const bf16x8*)&glB[(tt * 64 + dd) * 8];
      float occr[2];
#pragma unroll
      for (int rr = 0; rr < 2; ++rr)
        occr[rr] = socc[t][(R0 + rr) < 7 ? (R0 + rr) : 7];
      float kdqp[2] = {0.f, 0.f};
      float normp = 0.f;
#pragma unroll
      for (int n = 0; n < ETA; ++n) {
        float xs = bf2f(gA[n]);
        float dg = bf2f(gA[4 + n]);
        float qf = bf2f(gB[n]);
        if (w3) {
          fs[n] = fmaf(fs[n], dg, xs);
          normp = fmaf(fs[n], qf, normp);
        }
#pragma unroll
        for (int rr = 0; rr < 2; ++rr)
          if (rr < RN) {
            fk[rr][n] = fmaf(fk[rr][n], dg, xs * occr[rr]);
            kdqp[rr]  = fmaf(fk[rr][n], qf, kdqp[rr]);
          }
      }
      float vb = bf2f(gB[4]);
      float db = bf2f(gB[5]);
#pragma unroll
      for (int rr = 0; rr < 2; ++rr)
        if (rr < RN) fv[rr] = fmaf(fv[rr], db, vb * occr[rr]);

      // 2 butterfly sum-reductions per wave (w3: kdq6 + norm)
      float red[2];
      red[0] = kdqp[0];
      red[1] = w3 ? normp : kdqp[1];
#pragma unroll
      for (int i = 0; i < 2; ++i) {
        float x = red[i];
#pragma unroll
        for (int m = 1; m < 64; m <<= 1) x += __shfl_xor(x, m, 64);
        red[i] = x;
      }
      float kvvP = fv[0] * red[0];
      if (!w3) kvvP = fmaf(fv[1], red[1], kvvP);
      xch[w][tt][dd] = kvvP;
      if (w3) xch[4][tt][dd] = fmaf(14.f, red[1], 1e-5f);  // 2*R*norm + eps
    }
    __syncthreads();   // scan (glA reads + xch writes) complete
    // combine: wave w handles tt in {2w, 2w+1}; overlaps next stage
#pragma unroll
    for (int j = 0; j < 2; ++j) {
      int tt = w * 2 + j;
      int t = half * 8 + tt;
      float kvv = xch[0][tt][dd] + xch[1][tt][dd] + xch[2][tt][dd] + xch[3][tt][dd];
      attn[(size_t)(c * CHUNK + t) * 512 + h * 64 + dd] = f2bf(kvv / xch[4][tt][dd]);
    }
  }

  if (c == NCHUNK - 1) {
#pragma unroll
    for (int rr = 0; rr < 2; ++rr)
      if (rr < RN) {
#pragma unroll
        for (int n = 0; n < ETA; ++n)
          out[O_FK + (size_t)((R0 + rr) * NH + h) * 256 + n * 64 + dd] = fk[rr][n];
        out[O_FV + (size_t)((R0 + rr) * NH + h) * 64 + dd] = fv[rr];
      }
    if (w3) {
#pragma unroll
      for (int n = 0; n < ETA; ++n)
        out[O_FS + (size_t)h * 256 + n * 64 + dd] = fs[n];
    }
    if (w == 0 && h == 0 && dd == 0) out[O_TICK] = tick[0] + (float)T_SEQ;
  }
}

// ---------------------------------------------------------------------------
extern "C" void kernel_launch(void* const* d_in, const int* in_sizes, int n_in,
                              void* d_out, int out_size, void* d_ws, size_t ws_size,
                              hipStream_t stream) {
  const float* inputs = (const float*)d_in[0];
  const int*   term   = (const int*)d_in[1];
  const float* k_prev = (const float*)d_in[2];
  const float* v_prev = (const float*)d_in[3];
  const float* s_prev = (const float*)d_in[4];
  const float* tick   = (const float*)d_in[5];
  const float* W_kqv  = (const float*)d_in[6];
  const float* b_kqv  = (const float*)d_in[7];
  const float* W_p    = (const float*)d_in[8];
  const float* b_p    = (const float*)d_in[9];
  const float* W_proj = (const float*)d_in[10];
  const float* b_proj = (const float*)d_in[11];
  float* out = (float*)d_out;
  float* ws  = (float*)d_ws;

  short* kqvc   = (short*)(ws + KQVC_OFF);
  float* occ    = ws + OCC_OFF;
  short* BtProj = (short*)(ws + BTPROJ_OFF);
  short* attnbf = (short*)(ws + ATTNBF_OFF);
  float* biasc  = ws + BIASC_OFF;
  short* Abf    = (short*)(ws + ABF_OFF);
  short* BtCat  = (short*)(ws + BTCAT_OFF);
  short* ysum   = (short*)(ws + YSUM_OFF);   // overlays Abf/BtCat after GEMM
  short* carry  = (short*)(ws + CARRY_OFF);

  // 0) fused prologue: cast + transposes + bias concat + occil (1 dispatch)
  prologue<<<7291, 256, 0, stream>>>(inputs, Abf, W_kqv, W_p, W_proj,
                                     BtCat, BtProj, b_kqv, b_p, biasc,
                                     tick, occ);

  // 1) combined kqv+p projection (MFMA, bf16 out): N = 2688, 64² tiles
  gemm_bt_mfma<1><<<2688, 256, 0, stream>>>(Abf, BtCat, biasc, kqvc,
                                            T_SEQ, NKQVC, DIM);

  // 2) chunked linear scan (4-wave r-split, half-staged gates, bf16 states)
  pass_a<<<dim3(NCHUNK, NH), 256, 0, stream>>>(kqvc, occ, term, ysum);
  pass_b<<<78, 256, 0, stream>>>(ysum, carry, k_prev, v_prev, s_prev);
  pass_c<<<dim3(NCHUNK, NH), 256, 0, stream>>>(kqvc, occ, term, carry,
                                               attnbf, out, tick);

  // 3) output projection (MFMA, f32 out): 64² tiles
  gemm_bt_mfma<0><<<1024, 256, 0, stream>>>(attnbf, BtProj, b_proj, out,
                                            T_SEQ, DIM, NH * HDIM);
}

// Round 16
// 129.917 us; speedup vs baseline: 1.1417x; 1.1417x over previous
//
#include <hip/hip_runtime.h>
#include <hip/hip_bf16.h>
#include <math.h>

// Problem constants
#define T_SEQ 4096
#define DIM   1024
#define NH    8
#define HDIM  64
#define ETA   4
#define NR    7
#define NKQVC 2688   // combined: 2560 kqv + 96 p + 32 pad
#define CHUNK 16
#define NCHUNK 256   // T_SEQ / CHUNK

typedef __attribute__((ext_vector_type(8))) short bf16x8;
typedef __attribute__((ext_vector_type(4))) short short4v;
typedef __attribute__((ext_vector_type(4))) float f32x4;

// Workspace layout (float offsets).
// Permanent:
#define KQVC_OFF    0ul          // combined kqv+p bf16: 4096*2688 sh = 5,505,024 fl
#define OCC_OFF     5505024ul    // occ f32: 4096*8 = 32,768 fl
#define BTPROJ_OFF  5537792ul    // W_proj^T bf16: 1024*512 sh = 262,144 fl
#define ATTNBF_OFF  5799936ul    // attn bf16: 4096*512 sh = 1,048,576 fl
#define BIASC_OFF   6848512ul    // concat bias f32: 2,816 fl
// Transient A (dead after input GEMM):
#define ABF_OFF     6851328ul    // inputs bf16: 2,097,152 fl
#define BTCAT_OFF   8948480ul    // [2688][1024] bf16 = 1,376,256 fl
// Transient B (overlays transient A after GEMM), bf16:
#define YSUM_OFF    6851328ul    // 256*8*44*64 sh = 2,883,584 fl
#define CARRY_OFF   9734912ul    // 256*8*39*64 sh = 2,555,904 fl

// Output layout (float offsets), concatenated in return order
#define O_ATTN 0ul
#define O_FK   4194304ul   // (7,8,256)
#define O_FV   4208640ul   // (7,8,64)
#define O_FS   4212224ul   // (8,256)
#define O_TICK 4214272ul   // (1,)

__device__ __forceinline__ float sigm(float x) { return 1.f / (1.f + __expf(-x)); }

__device__ __forceinline__ short f2bf(float f) {
  union { __hip_bfloat16 b; short s; } u;
  u.b = __float2bfloat16(f);
  return u.s;
}
__device__ __forceinline__ float bf2f(short s) {
  union { __hip_bfloat16 b; short s2; } u;
  u.s2 = s;
  return __bfloat162float(u.b);
}

__device__ __forceinline__ void gload16(const void* g, void* l) {
  __builtin_amdgcn_global_load_lds(
      (const __attribute__((address_space(1))) void*)g,
      (__attribute__((address_space(3))) void*)l, 16, 0, 0);
}

// ---------------------------------------------------------------------------
// Fused prologue: one dispatch replaces cast + 3 transposes + bias + occil.
// ---------------------------------------------------------------------------
__global__ __launch_bounds__(256) void prologue(
    const float* __restrict__ inputs, short* __restrict__ Abf,
    const float* __restrict__ W_kqv, const float* __restrict__ W_p,
    const float* __restrict__ W_proj, short* __restrict__ BtCat,
    short* __restrict__ BtProj, const float* __restrict__ b_kqv,
    const float* __restrict__ b_p, float* __restrict__ biasc,
    const float* __restrict__ tick, float* __restrict__ occ) {
  const int b = blockIdx.x;
  const int tid = threadIdx.x;
  __shared__ float tile[32][33];
  const int tx = tid & 31, ty = tid >> 5;

  if (b < 4096) {
    size_t i = ((size_t)b * 256 + tid) * 4;
    float4 v = *(const float4*)(inputs + i);
    short4v o;
    o.x = f2bf(v.x); o.y = f2bf(v.y); o.z = f2bf(v.z); o.w = f2bf(v.w);
    *(short4v*)(Abf + i) = o;
  } else if (b < 6656) {
    int blk = b - 4096;
    int n0 = (blk % 80) * 32, k0 = (blk / 80) * 32;
    for (int i = ty; i < 32; i += 8)
      tile[i][tx] = W_kqv[(size_t)(k0 + i) * 2560 + n0 + tx];
    __syncthreads();
    for (int i = ty; i < 32; i += 8)
      BtCat[(size_t)(n0 + i) * 1024 + k0 + tx] = f2bf(tile[tx][i]);
  } else if (b < 6752) {
    int blk = b - 6656;
    int n0 = (blk % 3) * 32, k0 = (blk / 3) * 32;
    for (int i = ty; i < 32; i += 8)
      tile[i][tx] = W_p[(size_t)(k0 + i) * 96 + n0 + tx];
    __syncthreads();
    short* dst = BtCat + (size_t)2560 * 1024;
    for (int i = ty; i < 32; i += 8)
      dst[(size_t)(n0 + i) * 1024 + k0 + tx] = f2bf(tile[tx][i]);
  } else if (b < 7264) {
    int blk = b - 6752;
    int n0 = (blk % 32) * 32, k0 = (blk / 32) * 32;
    for (int i = ty; i < 32; i += 8)
      tile[i][tx] = W_proj[(size_t)(k0 + i) * 1024 + n0 + tx];
    __syncthreads();
    for (int i = ty; i < 32; i += 8)
      BtProj[(size_t)(n0 + i) * 512 + k0 + tx] = f2bf(tile[tx][i]);
  } else if (b < 7275) {
    int i = (b - 7264) * 256 + tid;
    if (i < NKQVC)
      biasc[i] = (i < 2560) ? b_kqv[i] : (i < 2656 ? b_p[i - 2560] : 0.f);
  } else {
    int t = (b - 7275) * 256 + tid;
    float tickt = tick[0] + (float)(t + 1);
#pragma unroll
    for (int r = 0; r < NR; ++r) {
      float om = (float)(-3.14159265358979323846 + r * (3.14159265358979323846 / 3.0));
      occ[t * 8 + r] = cosf(tickt * om);
    }
    occ[t * 8 + 7] = 0.f;
  }
}

// ---------------------------------------------------------------------------
// MFMA GEMM: C[M,N] = A[M,K] @ Bt[N,K]^T + bias.  A,Bt bf16.
// 128x128 tile, BK=32, 256 threads (4 waves 2x2), 16x16x32 MFMA.
// Double-buffered LDS staging, ONE barrier per K-step (measured-best R14
// config; 3-buf counted-vmcnt (R13) and 64² tile (R15) were <= neutral:
// this structure is jointly LDS-read-BW + latency bound at this shape).
// ---------------------------------------------------------------------------
template <int OUT_BF16>
__global__ __launch_bounds__(256) void gemm_bt_mfma(
    const short* __restrict__ A, const short* __restrict__ Bt,
    const float* __restrict__ bias, void* __restrict__ Cout,
    int M, int N, int K) {
  __shared__ __align__(16) short lds[16384];

  // XCD-aware bijective swizzle
  int nwg = gridDim.x;
  int cpx = nwg >> 3;
  int bid = blockIdx.x;
  int swz = (bid & 7) * cpx + (bid >> 3);
  int nbx = N >> 7;
  int bm0 = (swz / nbx) << 7;
  int bn0 = (swz % nbx) << 7;

  const int tid = threadIdx.x;
  const int w = tid >> 6, l = tid & 63;
  const int wm = w >> 1, wn = w & 1;
  const int fr = l & 15;
  const int fq = l >> 4;

  const int ca = w * 2;
  const short* Ag0 = A + (size_t)(bm0 + ca * 16 + (l >> 2)) * K + (l & 3) * 8;
  const short* Ag1 = Ag0 + (size_t)16 * K;
  const short* Bg0 = Bt + (size_t)(bn0 + ca * 16 + (l >> 2)) * K + (l & 3) * 8;
  const short* Bg1 = Bg0 + (size_t)16 * K;

  f32x4 acc[4][4];
#pragma unroll
  for (int mi = 0; mi < 4; ++mi)
#pragma unroll
    for (int ni = 0; ni < 4; ++ni)
#pragma unroll
      for (int r = 0; r < 4; ++r) acc[mi][ni][r] = 0.f;

  const int KT = K >> 5;
  int cur = 0;
  {
    short* la = &lds[ca * 512];
    short* lb = &lds[4096 + ca * 512];
    gload16(Ag0, la);
    gload16(Ag1, la + 512);
    gload16(Bg0, lb);
    gload16(Bg1, lb + 512);
  }
  __syncthreads();

  for (int kt = 0; kt < KT; ++kt) {
    if (kt + 1 < KT) {
      int nb = (cur ^ 1) * 8192;
      int ko = (kt + 1) * 32;
      short* la = &lds[nb + ca * 512];
      short* lb = &lds[nb + 4096 + ca * 512];
      gload16(Ag0 + ko, la);
      gload16(Ag1 + ko, la + 512);
      gload16(Bg0 + ko, lb);
      gload16(Bg1 + ko, lb + 512);
    }
    const short* ArP = &lds[cur * 8192 + (wm * 64 + fr) * 32 + fq * 8];
    const short* BrP = &lds[cur * 8192 + 4096 + (wn * 64 + fr) * 32 + fq * 8];
    bf16x8 af[4], bfv[4];
#pragma unroll
    for (int mi = 0; mi < 4; ++mi) af[mi] = *(const bf16x8*)(ArP + mi * 512);
#pragma unroll
    for (int ni = 0; ni < 4; ++ni) bfv[ni] = *(const bf16x8*)(BrP + ni * 512);
#pragma unroll
    for (int mi = 0; mi < 4; ++mi)
#pragma unroll
      for (int ni = 0; ni < 4; ++ni)
        acc[mi][ni] = __builtin_amdgcn_mfma_f32_16x16x32_bf16(
            af[mi], bfv[ni], acc[mi][ni], 0, 0, 0);
    __syncthreads();
    cur ^= 1;
  }

  // C/D layout: col = lane&15, row = (lane>>4)*4 + reg  [m89 verified]
  if (OUT_BF16) {
#pragma unroll
    for (int ni = 0; ni < 4; ++ni) {
      int col = wn * 64 + ni * 16 + fr;
      float bz = bias[bn0 + col];
#pragma unroll
      for (int mi = 0; mi < 4; ++mi) {
        int row = wm * 64 + mi * 16 + fq * 4;
#pragma unroll
        for (int r = 0; r < 4; ++r)
          lds[(row + r) * 128 + col] = f2bf(acc[mi][ni][r] + bz);
      }
    }
    __syncthreads();
    int row = tid >> 1, half = tid & 1;
    const f32x4* src = (const f32x4*)&lds[row * 128 + half * 64];
    f32x4* dst = (f32x4*)((short*)Cout + (size_t)(bm0 + row) * N + bn0 + half * 64);
#pragma unroll
    for (int i = 0; i < 8; ++i) dst[i] = src[i];
  } else {
#pragma unroll
    for (int ni = 0; ni < 4; ++ni) {
      int col = bn0 + wn * 64 + ni * 16 + fr;
      float bz = bias[col];
#pragma unroll
      for (int mi = 0; mi < 4; ++mi) {
        int row = bm0 + wm * 64 + mi * 16 + fq * 4;
#pragma unroll
        for (int r = 0; r < 4; ++r)
          ((float*)Cout)[(size_t)(row + r) * N + col] = acc[mi][ni][r] + bz;
      }
    }
  }
}

// ---------------------------------------------------------------------------
// Half-chunk gate staging: wave w computes gates for its 2 t's of this half
// at full 64-lane parallelism. Two CONTIGUOUS arrays (16 B/lane stride ->
// conflict-free b128):
//   glA[tt][dd][8] = xs0-3, dg0-3 ; glB[tt][dd][8] = qf0-3, vb, db, pad2.
// ---------------------------------------------------------------------------
__device__ __forceinline__ void stage_gates_half(
    const short* __restrict__ kqv, const int* __restrict__ term,
    short* glA, short* glB, int c, int h, int w, int dd, int half) {
#pragma unroll
  for (int j = 0; j < 2; ++j) {
    int tt = w * 2 + j;                 // 0..7
    int tg = c * CHUNK + half * 8 + tt;
    size_t base = (size_t)tg * NKQVC + h * 320 + dd;
    float kx = bf2f(kqv[base]);
    float qx = bf2f(kqv[base + 64]);
    float vx = bf2f(kqv[base + 128]);
    float bx = bf2f(kqv[base + 192]);
    float gx = bf2f(kqv[base + 256]);
    const short* pp = kqv + (size_t)tg * NKQVC + 2560 + h * 12;
    float nt = 1.f - (float)term[tg];
    float rk = fmaxf(kx, 0.f), rq = fmaxf(qx, 0.f);
    float sg = sigm(gx), sb = sigm(bx);
    bf16x8 oA, oB;
#pragma unroll
    for (int n = 0; n < 4; ++n) {
      float rp1 = fmaxf(bf2f(pp[n]), 0.f);
      float rp2 = fmaxf(bf2f(pp[4 + n]), 0.f);
      float sp3 = sigm(bf2f(pp[8 + n]));
      float gam = sg * sp3;
      oA[n]     = f2bf(rk * rp1 * gam);     // xs
      oA[4 + n] = f2bf((1.f - gam) * nt);   // dg
      oB[n]     = f2bf(rq * rp2);           // qf
    }
    oB[4] = f2bf(vx * sb);                  // vb
    oB[5] = f2bf((1.f - sb) * nt);          // db
    oB[6] = 0; oB[7] = 0;
    *(bf16x8*)&glA[(tt * 64 + dd) * 8] = oA;
    *(bf16x8*)&glB[(tt * 64 + dd) * 8] = oB;
  }
}

// ---------------------------------------------------------------------------
// Pass A (4-wave r-split, half-staged gates): wave w<3 owns r={2w,2w+1};
// wave 3 owns r=6 + fs/Pg/Pb. Per half: stage -> barrier -> scan -> barrier.
// ysum is bf16: [c][h][slot(44)][dd].
// ---------------------------------------------------------------------------
__global__ __launch_bounds__(256) void pass_a(
    const short* __restrict__ kqv, const float* __restrict__ occ,
    const int* __restrict__ term, short* __restrict__ ysum) {
  const int c = blockIdx.x, h = blockIdx.y;
  const int tid = threadIdx.x;
  const int w = tid >> 6, dd = tid & 63;
  const int R0 = w * 2;
  const int RN = (w == 3) ? 1 : 2;
  const bool w3 = (w == 3);
  __shared__ __align__(16) short glA[8 * 64 * 8];  // 8 KB
  __shared__ __align__(16) short glB[8 * 64 * 8];  // 8 KB
  __shared__ float socc[CHUNK][8];
  for (int i = tid; i < CHUNK * 8; i += 256)
    socc[i >> 3][i & 7] = occ[(size_t)c * CHUNK * 8 + i];

  float yk[2][ETA], yv[2], ys[ETA], Pg[ETA], Pb = 1.f;
#pragma unroll
  for (int rr = 0; rr < 2; ++rr) {
    yv[rr] = 0.f;
#pragma unroll
    for (int n = 0; n < ETA; ++n) yk[rr][n] = 0.f;
  }
#pragma unroll
  for (int n = 0; n < ETA; ++n) { ys[n] = 0.f; Pg[n] = 1.f; }

  for (int half = 0; half < 2; ++half) {
    stage_gates_half(kqv, term, glA, glB, c, h, w, dd, half);
    __syncthreads();
    for (int tt = 0; tt < 8; ++tt) {
      int t = half * 8 + tt;
      bf16x8 gA = *(const bf16x8*)&glA[(tt * 64 + dd) * 8];
      bf16x8 gB = *(const bf16x8*)&glB[(tt * 64 + dd) * 8];
      float occr[2];
#pragma unroll
      for (int rr = 0; rr < 2; ++rr)
        occr[rr] = socc[t][(R0 + rr) < 7 ? (R0 + rr) : 7];
#pragma unroll
      for (int n = 0; n < ETA; ++n) {
        float xs = bf2f(gA[n]);
        float dg = bf2f(gA[4 + n]);
        if (w3) {
          Pg[n] *= dg;
          ys[n] = fmaf(ys[n], dg, xs);
        }
#pragma unroll
        for (int rr = 0; rr < 2; ++rr)
          if (rr < RN) yk[rr][n] = fmaf(yk[rr][n], dg, xs * occr[rr]);
      }
      float vb = bf2f(gB[4]);
      float db = bf2f(gB[5]);
      if (w3) Pb *= db;
#pragma unroll
      for (int rr = 0; rr < 2; ++rr)
        if (rr < RN) yv[rr] = fmaf(yv[rr], db, vb * occr[rr]);
    }
    __syncthreads();   // scan done before next half's staging overwrites
  }

  short* o = ysum + (size_t)(c * NH + h) * 44 * 64 + dd;
#pragma unroll
  for (int rr = 0; rr < 2; ++rr)
    if (rr < RN) {
#pragma unroll
      for (int n = 0; n < ETA; ++n) o[((R0 + rr) * 4 + n) * 64] = f2bf(yk[rr][n]);
      o[(28 + R0 + rr) * 64] = f2bf(yv[rr]);
    }
  if (w3) {
#pragma unroll
    for (int n = 0; n < ETA; ++n) o[(35 + n) * 64] = f2bf(ys[n]);
#pragma unroll
    for (int n = 0; n < ETA; ++n) o[(39 + n) * 64] = f2bf(Pg[n]);
    o[43 * 64] = f2bf(Pb);
  }
}

// ---------------------------------------------------------------------------
// Pass B: carry propagation (f32 chain) from bf16 ysum into bf16 carry
// (separate __restrict__ buffer -> ring prefetch PD=16 batches).
// ---------------------------------------------------------------------------
__global__ __launch_bounds__(256) void pass_b(
    const short* __restrict__ ysum, short* __restrict__ carry,
    const float* __restrict__ k_prev, const float* __restrict__ v_prev,
    const float* __restrict__ s_prev) {
  int idx = blockIdx.x * 256 + threadIdx.x;
  int dd = idx & 63;
  int slot = (idx >> 6) % 39;
  int h = idx / (39 * 64);

  int pslot;
  float f;
  if (slot < 28) {
    int r = slot >> 2, n = slot & 3;
    f = k_prev[(size_t)(r * NH + h) * 256 + n * 64 + dd];
    pslot = 39 + n;
  } else if (slot < 35) {
    int r = slot - 28;
    f = v_prev[(size_t)(r * NH + h) * 64 + dd];
    pslot = 43;
  } else {
    int n = slot - 35;
    f = s_prev[(size_t)h * 256 + n * 64 + dd];
    pslot = 39 + n;
  }
  const size_t YSTR = (size_t)NH * 2816;
  const size_t CSTR = (size_t)NH * 2496;
  const short* yb = ysum + (size_t)h * 2816 + slot * 64 + dd;
  const short* pb = ysum + (size_t)h * 2816 + pslot * 64 + dd;
  short* cb = carry + (size_t)h * 2496 + slot * 64 + dd;

#define PD 16
  float yring[PD], pring[PD];
#pragma unroll
  for (int d = 0; d < PD; ++d) {
    yring[d] = bf2f(yb[(size_t)d * YSTR]);
    pring[d] = bf2f(pb[(size_t)d * YSTR]);
  }
  const int NB = NCHUNK / PD;
  for (int cb2 = 0; cb2 < NB; ++cb2) {
    int c0 = cb2 * PD;
    float ynext[PD], pnext[PD];
    if (cb2 + 1 < NB) {
#pragma unroll
      for (int j = 0; j < PD; ++j) {
        ynext[j] = bf2f(yb[(size_t)(c0 + PD + j) * YSTR]);
        pnext[j] = bf2f(pb[(size_t)(c0 + PD + j) * YSTR]);
      }
    }
#pragma unroll
    for (int j = 0; j < PD; ++j) {
      cb[(size_t)(c0 + j) * CSTR] = f2bf(f);
      f = fmaf(f, pring[j], yring[j]);
    }
    if (cb2 + 1 < NB) {
#pragma unroll
      for (int j = 0; j < PD; ++j) { yring[j] = ynext[j]; pring[j] = pnext[j]; }
    }
  }
#undef PD
}

// ---------------------------------------------------------------------------
// Pass C (4-wave r-split, half-staged gates, deferred combine).
// ---------------------------------------------------------------------------
__global__ __launch_bounds__(256) void pass_c(
    const short* __restrict__ kqv, const float* __restrict__ occ,
    const int* __restrict__ term, const short* __restrict__ carry,
    short* __restrict__ attn, float* __restrict__ out,
    const float* __restrict__ tick) {
  const int c = blockIdx.x, h = blockIdx.y;
  const int tid = threadIdx.x;
  const int w = tid >> 6, dd = tid & 63;
  const int R0 = w * 2;
  const int RN = (w == 3) ? 1 : 2;
  const bool w3 = (w == 3);
  __shared__ __align__(16) short glA[8 * 64 * 8];  // 8 KB
  __shared__ __align__(16) short glB[8 * 64 * 8];  // 8 KB
  __shared__ float socc[CHUNK][8];
  __shared__ float xch[5][8][64];   // [w partials 0..3 | denom][tt][dd]
  for (int i = tid; i < CHUNK * 8; i += 256)
    socc[i >> 3][i & 7] = occ[(size_t)c * CHUNK * 8 + i];

  const short* cp = carry + (size_t)(c * NH + h) * 2496 + dd;
  float fk[2][ETA], fv[2], fs[ETA];
#pragma unroll
  for (int rr = 0; rr < 2; ++rr)
    if (rr < RN) {
#pragma unroll
      for (int n = 0; n < ETA; ++n) fk[rr][n] = bf2f(cp[((R0 + rr) * 4 + n) * 64]);
      fv[rr] = bf2f(cp[(28 + R0 + rr) * 64]);
    }
  if (w3) {
#pragma unroll
    for (int n = 0; n < ETA; ++n) fs[n] = bf2f(cp[(35 + n) * 64]);
  }

  for (int half = 0; half < 2; ++half) {
    stage_gates_half(kqv, term, glA, glB, c, h, w, dd, half);
    __syncthreads();   // stage done AND previous combine's xch reads done
    for (int tt = 0; tt < 8; ++tt) {
      int t = half * 8 + tt;
      bf16x8 gA = *(const bf16x8*)&glA[(tt * 64 + dd) * 8];
      bf16x8 gB = *(const bf16x8*)&glB[(tt * 64 + dd) * 8];
      float occr[2];
#pragma unroll
      for (int rr = 0; rr < 2; ++rr)
        occr[rr] = socc[t][(R0 + rr) < 7 ? (R0 + rr) : 7];
      float kdqp[2] = {0.f, 0.f};
      float normp = 0.f;
#pragma unroll
      for (int n = 0; n < ETA; ++n) {
        float xs = bf2f(gA[n]);
        float dg = bf2f(gA[4 + n]);
        float qf = bf2f(gB[n]);
        if (w3) {
          fs[n] = fmaf(fs[n], dg, xs);
          normp = fmaf(fs[n], qf, normp);
        }
#pragma unroll
        for (int rr = 0; rr < 2; ++rr)
          if (rr < RN) {
            fk[rr][n] = fmaf(fk[rr][n], dg, xs * occr[rr]);
            kdqp[rr]  = fmaf(fk[rr][n], qf, kdqp[rr]);
          }
      }
      float vb = bf2f(gB[4]);
      float db = bf2f(gB[5]);
#pragma unroll
      for (int rr = 0; rr < 2; ++rr)
        if (rr < RN) fv[rr] = fmaf(fv[rr], db, vb * occr[rr]);

      // 2 butterfly sum-reductions per wave (w3: kdq6 + norm)
      float red[2];
      red[0] = kdqp[0];
      red[1] = w3 ? normp : kdqp[1];
#pragma unroll
      for (int i = 0; i < 2; ++i) {
        float x = red[i];
#pragma unroll
        for (int m = 1; m < 64; m <<= 1) x += __shfl_xor(x, m, 64);
        red[i] = x;
      }
      float kvvP = fv[0] * red[0];
      if (!w3) kvvP = fmaf(fv[1], red[1], kvvP);
      xch[w][tt][dd] = kvvP;
      if (w3) xch[4][tt][dd] = fmaf(14.f, red[1], 1e-5f);  // 2*R*norm + eps
    }
    __syncthreads();   // scan (glA reads + xch writes) complete
    // combine: wave w handles tt in {2w, 2w+1}; overlaps next stage
#pragma unroll
    for (int j = 0; j < 2; ++j) {
      int tt = w * 2 + j;
      int t = half * 8 + tt;
      float kvv = xch[0][tt][dd] + xch[1][tt][dd] + xch[2][tt][dd] + xch[3][tt][dd];
      attn[(size_t)(c * CHUNK + t) * 512 + h * 64 + dd] = f2bf(kvv / xch[4][tt][dd]);
    }
  }

  if (c == NCHUNK - 1) {
#pragma unroll
    for (int rr = 0; rr < 2; ++rr)
      if (rr < RN) {
#pragma unroll
        for (int n = 0; n < ETA; ++n)
          out[O_FK + (size_t)((R0 + rr) * NH + h) * 256 + n * 64 + dd] = fk[rr][n];
        out[O_FV + (size_t)((R0 + rr) * NH + h) * 64 + dd] = fv[rr];
      }
    if (w3) {
#pragma unroll
      for (int n = 0; n < ETA; ++n)
        out[O_FS + (size_t)h * 256 + n * 64 + dd] = fs[n];
    }
    if (w == 0 && h == 0 && dd == 0) out[O_TICK] = tick[0] + (float)T_SEQ;
  }
}

// ---------------------------------------------------------------------------
extern "C" void kernel_launch(void* const* d_in, const int* in_sizes, int n_in,
                              void* d_out, int out_size, void* d_ws, size_t ws_size,
                              hipStream_t stream) {
  const float* inputs = (const float*)d_in[0];
  const int*   term   = (const int*)d_in[1];
  const float* k_prev = (const float*)d_in[2];
  const float* v_prev = (const float*)d_in[3];
  const float* s_prev = (const float*)d_in[4];
  const float* tick   = (const float*)d_in[5];
  const float* W_kqv  = (const float*)d_in[6];
  const float* b_kqv  = (const float*)d_in[7];
  const float* W_p    = (const float*)d_in[8];
  const float* b_p    = (const float*)d_in[9];
  const float* W_proj = (const float*)d_in[10];
  const float* b_proj = (const float*)d_in[11];
  float* out = (float*)d_out;
  float* ws  = (float*)d_ws;

  short* kqvc   = (short*)(ws + KQVC_OFF);
  float* occ    = ws + OCC_OFF;
  short* BtProj = (short*)(ws + BTPROJ_OFF);
  short* attnbf = (short*)(ws + ATTNBF_OFF);
  float* biasc  = ws + BIASC_OFF;
  short* Abf    = (short*)(ws + ABF_OFF);
  short* BtCat  = (short*)(ws + BTCAT_OFF);
  short* ysum   = (short*)(ws + YSUM_OFF);   // overlays Abf/BtCat after GEMM
  short* carry  = (short*)(ws + CARRY_OFF);

  // 0) fused prologue: cast + transposes + bias concat + occil (1 dispatch)
  prologue<<<7291, 256, 0, stream>>>(inputs, Abf, W_kqv, W_p, W_proj,
                                     BtCat, BtProj, b_kqv, b_p, biasc,
                                     tick, occ);

  // 1) combined kqv+p projection (MFMA, bf16 out): N = 2688
  gemm_bt_mfma<1><<<672, 256, 0, stream>>>(Abf, BtCat, biasc, kqvc,
                                           T_SEQ, NKQVC, DIM);

  // 2) chunked linear scan (4-wave r-split, half-staged gates, bf16 states)
  pass_a<<<dim3(NCHUNK, NH), 256, 0, stream>>>(kqvc, occ, term, ysum);
  pass_b<<<78, 256, 0, stream>>>(ysum, carry, k_prev, v_prev, s_prev);
  pass_c<<<dim3(NCHUNK, NH), 256, 0, stream>>>(kqvc, occ, term, carry,
                                               attnbf, out, tick);

  // 3) output projection (MFMA, f32 out)
  gemm_bt_mfma<0><<<256, 256, 0, stream>>>(attnbf, BtProj, b_proj, out,
                                           T_SEQ, DIM, NH * HDIM);
}

// Round 17
// 126.740 us; speedup vs baseline: 1.1703x; 1.0251x over previous
//
#include <hip/hip_runtime.h>
#include <hip/hip_bf16.h>
#include <math.h>

// Problem constants
#define T_SEQ 4096
#define DIM   1024
#define NH    8
#define HDIM  64
#define ETA   4
#define NR    7
#define NKQVC 2688   // combined: 2560 kqv + 96 p + 32 pad
#define CHUNK 16
#define NCHUNK 256   // T_SEQ / CHUNK

typedef __attribute__((ext_vector_type(8))) short bf16x8;
typedef __attribute__((ext_vector_type(4))) short short4v;
typedef __attribute__((ext_vector_type(4))) float f32x4;

// Workspace layout (float offsets).
// Permanent:
#define KQVC_OFF    0ul          // combined kqv+p bf16: 4096*2688 sh = 5,505,024 fl
#define OCC_OFF     5505024ul    // occ f32: 4096*8 = 32,768 fl
#define BTPROJ_OFF  5537792ul    // W_proj^T bf16: 1024*512 sh = 262,144 fl
#define ATTNBF_OFF  5799936ul    // attn bf16: 4096*512 sh = 1,048,576 fl
#define BIASC_OFF   6848512ul    // concat bias f32: 2,816 fl
// Transient A (dead after input GEMM):
#define ABF_OFF     6851328ul    // inputs bf16: 2,097,152 fl
#define BTCAT_OFF   8948480ul    // [2688][1024] bf16 = 1,376,256 fl
// Transient B (overlays transient A after GEMM), bf16:
#define YSUM_OFF    6851328ul    // 256*8*44*64 sh = 2,883,584 fl
#define CARRY_OFF   9734912ul    // 256*8*39*64 sh = 2,555,904 fl

// Output layout (float offsets), concatenated in return order
#define O_ATTN 0ul
#define O_FK   4194304ul   // (7,8,256)
#define O_FV   4208640ul   // (7,8,64)
#define O_FS   4212224ul   // (8,256)
#define O_TICK 4214272ul   // (1,)

__device__ __forceinline__ float sigm(float x) { return 1.f / (1.f + __expf(-x)); }

__device__ __forceinline__ short f2bf(float f) {
  union { __hip_bfloat16 b; short s; } u;
  u.b = __float2bfloat16(f);
  return u.s;
}
__device__ __forceinline__ float bf2f(short s) {
  union { __hip_bfloat16 b; short s2; } u;
  u.s2 = s;
  return __bfloat162float(u.b);
}

__device__ __forceinline__ void gload16(const void* g, void* l) {
  __builtin_amdgcn_global_load_lds(
      (const __attribute__((address_space(1))) void*)g,
      (__attribute__((address_space(3))) void*)l, 16, 0, 0);
}

// ---------------------------------------------------------------------------
// Fused prologue: one dispatch replaces cast + 3 transposes + bias + occil.
// ---------------------------------------------------------------------------
__global__ __launch_bounds__(256) void prologue(
    const float* __restrict__ inputs, short* __restrict__ Abf,
    const float* __restrict__ W_kqv, const float* __restrict__ W_p,
    const float* __restrict__ W_proj, short* __restrict__ BtCat,
    short* __restrict__ BtProj, const float* __restrict__ b_kqv,
    const float* __restrict__ b_p, float* __restrict__ biasc,
    const float* __restrict__ tick, float* __restrict__ occ) {
  const int b = blockIdx.x;
  const int tid = threadIdx.x;
  __shared__ float tile[32][33];
  const int tx = tid & 31, ty = tid >> 5;

  if (b < 4096) {
    size_t i = ((size_t)b * 256 + tid) * 4;
    float4 v = *(const float4*)(inputs + i);
    short4v o;
    o.x = f2bf(v.x); o.y = f2bf(v.y); o.z = f2bf(v.z); o.w = f2bf(v.w);
    *(short4v*)(Abf + i) = o;
  } else if (b < 6656) {
    int blk = b - 4096;
    int n0 = (blk % 80) * 32, k0 = (blk / 80) * 32;
    for (int i = ty; i < 32; i += 8)
      tile[i][tx] = W_kqv[(size_t)(k0 + i) * 2560 + n0 + tx];
    __syncthreads();
    for (int i = ty; i < 32; i += 8)
      BtCat[(size_t)(n0 + i) * 1024 + k0 + tx] = f2bf(tile[tx][i]);
  } else if (b < 6752) {
    int blk = b - 6656;
    int n0 = (blk % 3) * 32, k0 = (blk / 3) * 32;
    for (int i = ty; i < 32; i += 8)
      tile[i][tx] = W_p[(size_t)(k0 + i) * 96 + n0 + tx];
    __syncthreads();
    short* dst = BtCat + (size_t)2560 * 1024;
    for (int i = ty; i < 32; i += 8)
      dst[(size_t)(n0 + i) * 1024 + k0 + tx] = f2bf(tile[tx][i]);
  } else if (b < 7264) {
    int blk = b - 6752;
    int n0 = (blk % 32) * 32, k0 = (blk / 32) * 32;
    for (int i = ty; i < 32; i += 8)
      tile[i][tx] = W_proj[(size_t)(k0 + i) * 1024 + n0 + tx];
    __syncthreads();
    for (int i = ty; i < 32; i += 8)
      BtProj[(size_t)(n0 + i) * 512 + k0 + tx] = f2bf(tile[tx][i]);
  } else if (b < 7275) {
    int i = (b - 7264) * 256 + tid;
    if (i < NKQVC)
      biasc[i] = (i < 2560) ? b_kqv[i] : (i < 2656 ? b_p[i - 2560] : 0.f);
  } else {
    int t = (b - 7275) * 256 + tid;
    float tickt = tick[0] + (float)(t + 1);
#pragma unroll
    for (int r = 0; r < NR; ++r) {
      float om = (float)(-3.14159265358979323846 + r * (3.14159265358979323846 / 3.0));
      occ[t * 8 + r] = cosf(tickt * om);
    }
    occ[t * 8 + 7] = 0.f;
  }
}

// ---------------------------------------------------------------------------
// MFMA GEMM: C[M,N] = A[M,K] @ Bt[N,K]^T + bias.  A,Bt bf16.
// 128x128 tile, BK=32, 512 threads (8 waves in a 2Mx4N grid; each wave owns
// a 64x32 sub-tile, 4x2 frags, 8 MFMA + 6 ds_read_b128 per K-step).
// Same grid/tile/LDS as the 4-wave R14 config but 2x the waves/CU (21 vs
// 10.5 at grid 672) for cross-block latency hiding — per-block arithmetic
// intensity unchanged (R15 showed smaller tiles lose on intensity).
// Double-buffered LDS staging, ONE barrier per K-step.
// ---------------------------------------------------------------------------
template <int OUT_BF16>
__global__ __launch_bounds__(512) void gemm_bt_mfma(
    const short* __restrict__ A, const short* __restrict__ Bt,
    const float* __restrict__ bias, void* __restrict__ Cout,
    int M, int N, int K) {
  __shared__ __align__(16) short lds[16384];

  // XCD-aware bijective swizzle (grid % 8 == 0)
  int nwg = gridDim.x;
  int cpx = nwg >> 3;
  int bid = blockIdx.x;
  int swz = (bid & 7) * cpx + (bid >> 3);
  int nbx = N >> 7;
  int bm0 = (swz / nbx) << 7;
  int bn0 = (swz % nbx) << 7;

  const int tid = threadIdx.x;
  const int w = tid >> 6, l = tid & 63;
  const int wm = w >> 2, wn = w & 3;   // 2x4 wave grid; each wave 64x32 out
  const int fr = l & 15;
  const int fq = l >> 4;

  // staging: wave w stages A rows [16w,16w+16) and B rows [16w,16w+16)
  const short* Ag = A + (size_t)(bm0 + w * 16 + (l >> 2)) * K + (l & 3) * 8;
  const short* Bg = Bt + (size_t)(bn0 + w * 16 + (l >> 2)) * K + (l & 3) * 8;

  f32x4 acc[4][2];
#pragma unroll
  for (int mi = 0; mi < 4; ++mi)
#pragma unroll
    for (int ni = 0; ni < 2; ++ni)
#pragma unroll
      for (int r = 0; r < 4; ++r) acc[mi][ni][r] = 0.f;

  const int KT = K >> 5;
  int cur = 0;
  gload16(Ag, &lds[w * 512]);
  gload16(Bg, &lds[4096 + w * 512]);
  __syncthreads();

  for (int kt = 0; kt < KT; ++kt) {
    if (kt + 1 < KT) {
      int nb = (cur ^ 1) * 8192;
      int ko = (kt + 1) * 32;
      gload16(Ag + ko, &lds[nb + w * 512]);
      gload16(Bg + ko, &lds[nb + 4096 + w * 512]);
    }
    const short* ArP = &lds[cur * 8192 + (wm * 64 + fr) * 32 + fq * 8];
    const short* BrP = &lds[cur * 8192 + 4096 + (wn * 32 + fr) * 32 + fq * 8];
    bf16x8 af[4], bfv[2];
#pragma unroll
    for (int mi = 0; mi < 4; ++mi) af[mi] = *(const bf16x8*)(ArP + mi * 512);
#pragma unroll
    for (int ni = 0; ni < 2; ++ni) bfv[ni] = *(const bf16x8*)(BrP + ni * 512);
#pragma unroll
    for (int mi = 0; mi < 4; ++mi)
#pragma unroll
      for (int ni = 0; ni < 2; ++ni)
        acc[mi][ni] = __builtin_amdgcn_mfma_f32_16x16x32_bf16(
            af[mi], bfv[ni], acc[mi][ni], 0, 0, 0);
    __syncthreads();
    cur ^= 1;
  }

  // C/D layout: col = lane&15, row = (lane>>4)*4 + reg  [m89 verified]
  if (OUT_BF16) {
    // stage C tile (128x128 bf16 = 32 KB) in LDS, then coalesced 16B stores
#pragma unroll
    for (int ni = 0; ni < 2; ++ni) {
      int col = wn * 32 + ni * 16 + fr;
      float bz = bias[bn0 + col];
#pragma unroll
      for (int mi = 0; mi < 4; ++mi) {
        int row = wm * 64 + mi * 16 + fq * 4;
#pragma unroll
        for (int r = 0; r < 4; ++r)
          lds[(row + r) * 128 + col] = f2bf(acc[mi][ni][r] + bz);
      }
    }
    __syncthreads();
    int row = tid >> 2, seg = tid & 3;   // 512 threads: 128 rows x 4 segs
    const bf16x8* src = (const bf16x8*)&lds[row * 128 + seg * 32];
    short* dst = (short*)Cout + (size_t)(bm0 + row) * N + bn0 + seg * 32;
    *(bf16x8*)dst = src[0];
    *(bf16x8*)(dst + 8) = src[1];
  } else {
#pragma unroll
    for (int ni = 0; ni < 2; ++ni) {
      int col = bn0 + wn * 32 + ni * 16 + fr;
      float bz = bias[col];
#pragma unroll
      for (int mi = 0; mi < 4; ++mi) {
        int row = bm0 + wm * 64 + mi * 16 + fq * 4;
#pragma unroll
        for (int r = 0; r < 4; ++r)
          ((float*)Cout)[(size_t)(row + r) * N + col] = acc[mi][ni][r] + bz;
      }
    }
  }
}

// ---------------------------------------------------------------------------
// Half-chunk gate staging: wave w computes gates for its 2 t's of this half
// at full 64-lane parallelism. Two CONTIGUOUS arrays (16 B/lane stride ->
// conflict-free b128):
//   glA[tt][dd][8] = xs0-3, dg0-3 ; glB[tt][dd][8] = qf0-3, vb, db, pad2.
// ---------------------------------------------------------------------------
__device__ __forceinline__ void stage_gates_half(
    const short* __restrict__ kqv, const int* __restrict__ term,
    short* glA, short* glB, int c, int h, int w, int dd, int half) {
#pragma unroll
  for (int j = 0; j < 2; ++j) {
    int tt = w * 2 + j;                 // 0..7
    int tg = c * CHUNK + half * 8 + tt;
    size_t base = (size_t)tg * NKQVC + h * 320 + dd;
    float kx = bf2f(kqv[base]);
    float qx = bf2f(kqv[base + 64]);
    float vx = bf2f(kqv[base + 128]);
    float bx = bf2f(kqv[base + 192]);
    float gx = bf2f(kqv[base + 256]);
    const short* pp = kqv + (size_t)tg * NKQVC + 2560 + h * 12;
    float nt = 1.f - (float)term[tg];
    float rk = fmaxf(kx, 0.f), rq = fmaxf(qx, 0.f);
    float sg = sigm(gx), sb = sigm(bx);
    bf16x8 oA, oB;
#pragma unroll
    for (int n = 0; n < 4; ++n) {
      float rp1 = fmaxf(bf2f(pp[n]), 0.f);
      float rp2 = fmaxf(bf2f(pp[4 + n]), 0.f);
      float sp3 = sigm(bf2f(pp[8 + n]));
      float gam = sg * sp3;
      oA[n]     = f2bf(rk * rp1 * gam);     // xs
      oA[4 + n] = f2bf((1.f - gam) * nt);   // dg
      oB[n]     = f2bf(rq * rp2);           // qf
    }
    oB[4] = f2bf(vx * sb);                  // vb
    oB[5] = f2bf((1.f - sb) * nt);          // db
    oB[6] = 0; oB[7] = 0;
    *(bf16x8*)&glA[(tt * 64 + dd) * 8] = oA;
    *(bf16x8*)&glB[(tt * 64 + dd) * 8] = oB;
  }
}

// ---------------------------------------------------------------------------
// Pass A (4-wave r-split, half-staged gates): wave w<3 owns r={2w,2w+1};
// wave 3 owns r=6 + fs/Pg/Pb. Per half: stage -> barrier -> scan -> barrier.
// ysum is bf16: [c][h][slot(44)][dd].
// ---------------------------------------------------------------------------
__global__ __launch_bounds__(256) void pass_a(
    const short* __restrict__ kqv, const float* __restrict__ occ,
    const int* __restrict__ term, short* __restrict__ ysum) {
  const int c = blockIdx.x, h = blockIdx.y;
  const int tid = threadIdx.x;
  const int w = tid >> 6, dd = tid & 63;
  const int R0 = w * 2;
  const int RN = (w == 3) ? 1 : 2;
  const bool w3 = (w == 3);
  __shared__ __align__(16) short glA[8 * 64 * 8];  // 8 KB
  __shared__ __align__(16) short glB[8 * 64 * 8];  // 8 KB
  __shared__ float socc[CHUNK][8];
  for (int i = tid; i < CHUNK * 8; i += 256)
    socc[i >> 3][i & 7] = occ[(size_t)c * CHUNK * 8 + i];

  float yk[2][ETA], yv[2], ys[ETA], Pg[ETA], Pb = 1.f;
#pragma unroll
  for (int rr = 0; rr < 2; ++rr) {
    yv[rr] = 0.f;
#pragma unroll
    for (int n = 0; n < ETA; ++n) yk[rr][n] = 0.f;
  }
#pragma unroll
  for (int n = 0; n < ETA; ++n) { ys[n] = 0.f; Pg[n] = 1.f; }

  for (int half = 0; half < 2; ++half) {
    stage_gates_half(kqv, term, glA, glB, c, h, w, dd, half);
    __syncthreads();
    for (int tt = 0; tt < 8; ++tt) {
      int t = half * 8 + tt;
      bf16x8 gA = *(const bf16x8*)&glA[(tt * 64 + dd) * 8];
      bf16x8 gB = *(const bf16x8*)&glB[(tt * 64 + dd) * 8];
      float occr[2];
#pragma unroll
      for (int rr = 0; rr < 2; ++rr)
        occr[rr] = socc[t][(R0 + rr) < 7 ? (R0 + rr) : 7];
#pragma unroll
      for (int n = 0; n < ETA; ++n) {
        float xs = bf2f(gA[n]);
        float dg = bf2f(gA[4 + n]);
        if (w3) {
          Pg[n] *= dg;
          ys[n] = fmaf(ys[n], dg, xs);
        }
#pragma unroll
        for (int rr = 0; rr < 2; ++rr)
          if (rr < RN) yk[rr][n] = fmaf(yk[rr][n], dg, xs * occr[rr]);
      }
      float vb = bf2f(gB[4]);
      float db = bf2f(gB[5]);
      if (w3) Pb *= db;
#pragma unroll
      for (int rr = 0; rr < 2; ++rr)
        if (rr < RN) yv[rr] = fmaf(yv[rr], db, vb * occr[rr]);
    }
    __syncthreads();   // scan done before next half's staging overwrites
  }

  short* o = ysum + (size_t)(c * NH + h) * 44 * 64 + dd;
#pragma unroll
  for (int rr = 0; rr < 2; ++rr)
    if (rr < RN) {
#pragma unroll
      for (int n = 0; n < ETA; ++n) o[((R0 + rr) * 4 + n) * 64] = f2bf(yk[rr][n]);
      o[(28 + R0 + rr) * 64] = f2bf(yv[rr]);
    }
  if (w3) {
#pragma unroll
    for (int n = 0; n < ETA; ++n) o[(35 + n) * 64] = f2bf(ys[n]);
#pragma unroll
    for (int n = 0; n < ETA; ++n) o[(39 + n) * 64] = f2bf(Pg[n]);
    o[43 * 64] = f2bf(Pb);
  }
}

// ---------------------------------------------------------------------------
// Pass B: carry propagation (f32 chain) from bf16 ysum into bf16 carry
// (separate __restrict__ buffer -> ring prefetch PD=16 batches).
// ---------------------------------------------------------------------------
__global__ __launch_bounds__(256) void pass_b(
    const short* __restrict__ ysum, short* __restrict__ carry,
    const float* __restrict__ k_prev, const float* __restrict__ v_prev,
    const float* __restrict__ s_prev) {
  int idx = blockIdx.x * 256 + threadIdx.x;
  int dd = idx & 63;
  int slot = (idx >> 6) % 39;
  int h = idx / (39 * 64);

  int pslot;
  float f;
  if (slot < 28) {
    int r = slot >> 2, n = slot & 3;
    f = k_prev[(size_t)(r * NH + h) * 256 + n * 64 + dd];
    pslot = 39 + n;
  } else if (slot < 35) {
    int r = slot - 28;
    f = v_prev[(size_t)(r * NH + h) * 64 + dd];
    pslot = 43;
  } else {
    int n = slot - 35;
    f = s_prev[(size_t)h * 256 + n * 64 + dd];
    pslot = 39 + n;
  }
  const size_t YSTR = (size_t)NH * 2816;
  const size_t CSTR = (size_t)NH * 2496;
  const short* yb = ysum + (size_t)h * 2816 + slot * 64 + dd;
  const short* pb = ysum + (size_t)h * 2816 + pslot * 64 + dd;
  short* cb = carry + (size_t)h * 2496 + slot * 64 + dd;

#define PD 16
  float yring[PD], pring[PD];
#pragma unroll
  for (int d = 0; d < PD; ++d) {
    yring[d] = bf2f(yb[(size_t)d * YSTR]);
    pring[d] = bf2f(pb[(size_t)d * YSTR]);
  }
  const int NB = NCHUNK / PD;
  for (int cb2 = 0; cb2 < NB; ++cb2) {
    int c0 = cb2 * PD;
    float ynext[PD], pnext[PD];
    if (cb2 + 1 < NB) {
#pragma unroll
      for (int j = 0; j < PD; ++j) {
        ynext[j] = bf2f(yb[(size_t)(c0 + PD + j) * YSTR]);
        pnext[j] = bf2f(pb[(size_t)(c0 + PD + j) * YSTR]);
      }
    }
#pragma unroll
    for (int j = 0; j < PD; ++j) {
      cb[(size_t)(c0 + j) * CSTR] = f2bf(f);
      f = fmaf(f, pring[j], yring[j]);
    }
    if (cb2 + 1 < NB) {
#pragma unroll
      for (int j = 0; j < PD; ++j) { yring[j] = ynext[j]; pring[j] = pnext[j]; }
    }
  }
#undef PD
}

// ---------------------------------------------------------------------------
// Pass C (4-wave r-split, half-staged gates, deferred combine).
// ---------------------------------------------------------------------------
__global__ __launch_bounds__(256) void pass_c(
    const short* __restrict__ kqv, const float* __restrict__ occ,
    const int* __restrict__ term, const short* __restrict__ carry,
    short* __restrict__ attn, float* __restrict__ out,
    const float* __restrict__ tick) {
  const int c = blockIdx.x, h = blockIdx.y;
  const int tid = threadIdx.x;
  const int w = tid >> 6, dd = tid & 63;
  const int R0 = w * 2;
  const int RN = (w == 3) ? 1 : 2;
  const bool w3 = (w == 3);
  __shared__ __align__(16) short glA[8 * 64 * 8];  // 8 KB
  __shared__ __align__(16) short glB[8 * 64 * 8];  // 8 KB
  __shared__ float socc[CHUNK][8];
  __shared__ float xch[5][8][64];   // [w partials 0..3 | denom][tt][dd]
  for (int i = tid; i < CHUNK * 8; i += 256)
    socc[i >> 3][i & 7] = occ[(size_t)c * CHUNK * 8 + i];

  const short* cp = carry + (size_t)(c * NH + h) * 2496 + dd;
  float fk[2][ETA], fv[2], fs[ETA];
#pragma unroll
  for (int rr = 0; rr < 2; ++rr)
    if (rr < RN) {
#pragma unroll
      for (int n = 0; n < ETA; ++n) fk[rr][n] = bf2f(cp[((R0 + rr) * 4 + n) * 64]);
      fv[rr] = bf2f(cp[(28 + R0 + rr) * 64]);
    }
  if (w3) {
#pragma unroll
    for (int n = 0; n < ETA; ++n) fs[n] = bf2f(cp[(35 + n) * 64]);
  }

  for (int half = 0; half < 2; ++half) {
    stage_gates_half(kqv, term, glA, glB, c, h, w, dd, half);
    __syncthreads();   // stage done AND previous combine's xch reads done
    for (int tt = 0; tt < 8; ++tt) {
      int t = half * 8 + tt;
      bf16x8 gA = *(const bf16x8*)&glA[(tt * 64 + dd) * 8];
      bf16x8 gB = *(const bf16x8*)&glB[(tt * 64 + dd) * 8];
      float occr[2];
#pragma unroll
      for (int rr = 0; rr < 2; ++rr)
        occr[rr] = socc[t][(R0 + rr) < 7 ? (R0 + rr) : 7];
      float kdqp[2] = {0.f, 0.f};
      float normp = 0.f;
#pragma unroll
      for (int n = 0; n < ETA; ++n) {
        float xs = bf2f(gA[n]);
        float dg = bf2f(gA[4 + n]);
        float qf = bf2f(gB[n]);
        if (w3) {
          fs[n] = fmaf(fs[n], dg, xs);
          normp = fmaf(fs[n], qf, normp);
        }
#pragma unroll
        for (int rr = 0; rr < 2; ++rr)
          if (rr < RN) {
            fk[rr][n] = fmaf(fk[rr][n], dg, xs * occr[rr]);
            kdqp[rr]  = fmaf(fk[rr][n], qf, kdqp[rr]);
          }
      }
      float vb = bf2f(gB[4]);
      float db = bf2f(gB[5]);
#pragma unroll
      for (int rr = 0; rr < 2; ++rr)
        if (rr < RN) fv[rr] = fmaf(fv[rr], db, vb * occr[rr]);

      // 2 butterfly sum-reductions per wave (w3: kdq6 + norm)
      float red[2];
      red[0] = kdqp[0];
      red[1] = w3 ? normp : kdqp[1];
#pragma unroll
      for (int i = 0; i < 2; ++i) {
        float x = red[i];
#pragma unroll
        for (int m = 1; m < 64; m <<= 1) x += __shfl_xor(x, m, 64);
        red[i] = x;
      }
      float kvvP = fv[0] * red[0];
      if (!w3) kvvP = fmaf(fv[1], red[1], kvvP);
      xch[w][tt][dd] = kvvP;
      if (w3) xch[4][tt][dd] = fmaf(14.f, red[1], 1e-5f);  // 2*R*norm + eps
    }
    __syncthreads();   // scan (glA reads + xch writes) complete
    // combine: wave w handles tt in {2w, 2w+1}; overlaps next stage
#pragma unroll
    for (int j = 0; j < 2; ++j) {
      int tt = w * 2 + j;
      int t = half * 8 + tt;
      float kvv = xch[0][tt][dd] + xch[1][tt][dd] + xch[2][tt][dd] + xch[3][tt][dd];
      attn[(size_t)(c * CHUNK + t) * 512 + h * 64 + dd] = f2bf(kvv / xch[4][tt][dd]);
    }
  }

  if (c == NCHUNK - 1) {
#pragma unroll
    for (int rr = 0; rr < 2; ++rr)
      if (rr < RN) {
#pragma unroll
        for (int n = 0; n < ETA; ++n)
          out[O_FK + (size_t)((R0 + rr) * NH + h) * 256 + n * 64 + dd] = fk[rr][n];
        out[O_FV + (size_t)((R0 + rr) * NH + h) * 64 + dd] = fv[rr];
      }
    if (w3) {
#pragma unroll
      for (int n = 0; n < ETA; ++n)
        out[O_FS + (size_t)h * 256 + n * 64 + dd] = fs[n];
    }
    if (w == 0 && h == 0 && dd == 0) out[O_TICK] = tick[0] + (float)T_SEQ;
  }
}

// ---------------------------------------------------------------------------
extern "C" void kernel_launch(void* const* d_in, const int* in_sizes, int n_in,
                              void* d_out, int out_size, void* d_ws, size_t ws_size,
                              hipStream_t stream) {
  const float* inputs = (const float*)d_in[0];
  const int*   term   = (const int*)d_in[1];
  const float* k_prev = (const float*)d_in[2];
  const float* v_prev = (const float*)d_in[3];
  const float* s_prev = (const float*)d_in[4];
  const float* tick   = (const float*)d_in[5];
  const float* W_kqv  = (const float*)d_in[6];
  const float* b_kqv  = (const float*)d_in[7];
  const float* W_p    = (const float*)d_in[8];
  const float* b_p    = (const float*)d_in[9];
  const float* W_proj = (const float*)d_in[10];
  const float* b_proj = (const float*)d_in[11];
  float* out = (float*)d_out;
  float* ws  = (float*)d_ws;

  short* kqvc   = (short*)(ws + KQVC_OFF);
  float* occ    = ws + OCC_OFF;
  short* BtProj = (short*)(ws + BTPROJ_OFF);
  short* attnbf = (short*)(ws + ATTNBF_OFF);
  float* biasc  = ws + BIASC_OFF;
  short* Abf    = (short*)(ws + ABF_OFF);
  short* BtCat  = (short*)(ws + BTCAT_OFF);
  short* ysum   = (short*)(ws + YSUM_OFF);   // overlays Abf/BtCat after GEMM
  short* carry  = (short*)(ws + CARRY_OFF);

  // 0) fused prologue: cast + transposes + bias concat + occil (1 dispatch)
  prologue<<<7291, 256, 0, stream>>>(inputs, Abf, W_kqv, W_p, W_proj,
                                     BtCat, BtProj, b_kqv, b_p, biasc,
                                     tick, occ);

  // 1) combined kqv+p projection (MFMA, bf16 out): N = 2688, 8-wave blocks
  gemm_bt_mfma<1><<<672, 512, 0, stream>>>(Abf, BtCat, biasc, kqvc,
                                           T_SEQ, NKQVC, DIM);

  // 2) chunked linear scan (4-wave r-split, half-staged gates, bf16 states)
  pass_a<<<dim3(NCHUNK, NH), 256, 0, stream>>>(kqvc, occ, term, ysum);
  pass_b<<<78, 256, 0, stream>>>(ysum, carry, k_prev, v_prev, s_prev);
  pass_c<<<dim3(NCHUNK, NH), 256, 0, stream>>>(kqvc, occ, term, carry,
                                               attnbf, out, tick);

  // 3) output projection (MFMA, f32 out): 8-wave blocks
  gemm_bt_mfma<0><<<256, 512, 0, stream>>>(attnbf, BtProj, b_proj, out,
                                           T_SEQ, DIM, NH * HDIM);
}